// Round 14
// baseline (135.898 us; speedup 1.0000x reference)
//
#include <hip/hip_runtime.h>
#include <math.h>

// ---- geometry ----
// Grid 50^3, coords shifted +1 -> occupy [1,50]. Dense key = (z*GY+y)*64+x.
#define GY 54
#define ZD 58
#define NROWS (ZD*GY*64)      // 200448 keys

// half-brick 8x4x4 = 128 outputs per block (2 waves); halo 10x6x6 = 360 rows.
#define HX 10
#define HY 6
#define HXY 60                // halo rows per z-slice
#define NH2 360               // halo rows per half-brick
#define NBX 7
#define NBY 13
#define NBZ2 13               // z-bricks of 4 output slices (covers z 1..52)
#define NBLK (NBX*NBY*NBZ2)   // 1183
#define SLABH 148             // ceil(1183/8)

#define K3CC (27*64*64)       // 110592 weight elements

typedef __bf16  bf16x8 __attribute__((ext_vector_type(8)));
typedef float  f32x16 __attribute__((ext_vector_type(16)));

// global->LDS DMA, 16B per lane, linear LDS dest (wave-uniform base + lane*16)
#define AS1 __attribute__((address_space(1)))
#define AS3 __attribute__((address_space(3)))
#define GLD_LDS16(g, l) \
    __builtin_amdgcn_global_load_lds((const AS1 void*)(g), (AS3 void*)(l), 16, 0, 0)

// ---- fused prep: maps + reverse keys + Wt4 + feats->bf16 + zero row ----
__global__ void prep_kernel(const float* __restrict__ ipos, int n,
                            const float* __restrict__ opos, int m,
                            const float* __restrict__ vsp,
                            const float* __restrict__ W,
                            const float* __restrict__ feats,
                            int* __restrict__ imap, int* __restrict__ ikey,
                            int* __restrict__ omap, int* __restrict__ okey,
                            __bf16* __restrict__ Wt4,
                            __bf16* __restrict__ zrow,
                            __bf16* __restrict__ featsB) {
    int i = blockIdx.x * 256 + threadIdx.x;
    float vs = vsp[0];
    if (i < n) {
        int x = (int)floorf(ipos[3*i+0] / vs) + 1;
        int y = (int)floorf(ipos[3*i+1] / vs) + 1;
        int z = (int)floorf(ipos[3*i+2] / vs) + 1;
        int key = (z * GY + y) * 64 + x;
        ikey[i] = key;
        imap[key] = i;
    } else if (i < n + m) {
        int j = i - n;
        int x = (int)floorf(opos[3*j+0] / vs) + 1;
        int y = (int)floorf(opos[3*j+1] / vs) + 1;
        int z = (int)floorf(opos[3*j+2] / vs) + 1;
        int key = (z * GY + y) * 64 + x;
        okey[j] = key;
        omap[key] = j;
    } else if (i < n + m + K3CC) {
        int k  = i - n - m;
        int t  = k >> 12;
        int r  = k & 4095;
        int ci = r >> 6;
        int co = r & 63;
        int p   = ci >> 4;
        int cil = ci & 15;
        Wt4[(((p * 27 + t) << 6) + co) * 16 + cil] = (__bf16)W[k];
    } else if (i < n + m + K3CC + 32) {
        zrow[i - n - m - K3CC] = (__bf16)0.f;
    } else {
        int j = i - n - m - K3CC - 32;         // one bf16x8 chunk of featsB
        if (j < n * 8) {
            const float4* s = (const float4*)(feats + (size_t)j * 8);
            float4 f0 = s[0], f1 = s[1];
            bf16x8 v;
            v[0]=(__bf16)f0.x; v[1]=(__bf16)f0.y; v[2]=(__bf16)f0.z; v[3]=(__bf16)f0.w;
            v[4]=(__bf16)f1.x; v[5]=(__bf16)f1.y; v[6]=(__bf16)f1.z; v[7]=(__bf16)f1.w;
            *(bf16x8*)(featsB + (size_t)j * 8) = v;
        }
    }
}

// r12 structure + z-reuse A-hoisting FORCED via empty-asm keep-alive fence.
// r13 lesson: with plain loads the backend REMATERIALIZES the ds_reads
// (conflict counter stayed bit-identical at 1183x432x8) rather than keep 4
// quads live across 12 MFMAs. The "+v" asm makes the values asm outputs --
// re-reading LDS can no longer be proven equivalent, so they must stay in
// registers. Zero instructions emitted. Explicit dz bodies (no ternaries).
// Closed models: conflict tally @32B stride = exactly 8/read (wave64-b128
// floor); B-loads compiler-pipelined (r10 null); manual ILP hurts (r11).
// Per-CU pipe sum: TA ~15us + LDS ~13us + MFMA ~13us + VALU ~4.5us ~= 45us
// ~= measured 50 at 2.3 waves/SIMD. This round harvests LDS 13->8.7us.
// (128,2): never squeeze the allocator (min-waves>=3 spilled twice).
__global__ __launch_bounds__(128, 2) void conv_kernel(
    const __bf16* __restrict__ featsB,  // [N,64] bf16
    const __bf16* __restrict__ Wt4,     // [4][27][64cout][16cin]
    const __bf16* __restrict__ zrow,    // 32 zero bf16
    const float* __restrict__ bias,     // [64]
    const int*   __restrict__ imap,
    const int*   __restrict__ ikey,
    const int*   __restrict__ omap,
    const int*   __restrict__ okey,
    float*       __restrict__ out,      // [M,64]
    int N, int M)
{
    __shared__ __align__(16) __bf16 halo[2 * NH2 * 16];       // 23040 B (double-buffered)
    __shared__ int ridx[NH2];                                 //  1440 B
    __shared__ int obuf[128];                                 //   512 B
    // total ~25.0 KB -> 6 blocks/CU capacity; grid needs ~4.6 -> all co-resident

    const int tid = threadIdx.x;

    // XCD slab swizzle
    int q = (blockIdx.x & 7) * SLABH + (blockIdx.x >> 3);
    if (q >= NBLK) return;   // block-uniform exit before any barrier
    const int bx = q % NBX;
    int rem = q / NBX;
    const int by  = rem % NBY;
    const int bz2 = rem / NBY;          // z-origin = bz2*4

    // ---- resolve halo row indices (validated) + output rows ----
    #pragma unroll
    for (int it = 0; it < 3; ++it) {
        int r = it * 128 + tid;
        if (r < NH2) {
            int xs = r % HX;
            int t2 = r / HX;
            int ys = t2 % HY;
            int zs = t2 / HY;           // [0,6)
            int key = ((bz2*4 + zs) * GY + (by*4 + ys)) * 64 + (bx*8 + xs);
            int idx = imap[key];
            int c = min(max(idx, 0), N - 1);
            ridx[r] = (idx >= 0 && idx < N && ikey[c] == key) ? idx : -1;
        }
    }
    {
        int x = tid & 7, y = (tid >> 3) & 3, z2 = tid >> 5;   // z2 in [0,4)
        int key = ((bz2*4 + z2 + 1) * GY + (by*4 + y + 1)) * 64 + (bx*8 + x + 1);
        int o = omap[key];
        int c = min(max(o, 0), M - 1);
        obuf[tid] = (o >= 0 && o < M && okey[c] == key) ? o : -1;
    }

    // compute roles: wave w (of 2) owns output z-slices {2w, 2w+1} x both n-tiles
    const int wave  = tid >> 6;         // {0,1}
    const int lane  = tid & 63;
    const int lrow  = lane & 31;
    const int halfk = lane >> 5;
    const int xv = lrow & 7, yv = (lrow >> 3) & 3;
    const int arow0 = (2*wave + 1) * HXY + (yv + 1) * HX + (xv + 1);

    f32x16 acc00, acc01, acc10, acc11;
    #pragma unroll
    for (int i = 0; i < 16; ++i) { acc00[i]=0.f; acc01[i]=0.f; acc10[i]=0.f; acc11[i]=0.f; }

    __syncthreads();   // ridx + obuf visible

    // ---- prologue: DMA halo quarter p=0 into buf0 (720 tasks) ----
    #pragma unroll
    for (int it = 0; it < 6; ++it) {
        int task = it * 128 + tid;
        if (task < NH2 * 2) {
            int r  = task >> 1;
            int hl = task & 1;
            int idx = ridx[r];
            const __bf16* src = (idx >= 0) ? featsB + (size_t)idx * 64 + hl * 8
                                           : zrow;
            GLD_LDS16(src, (char*)halo + task * 16);
        }
    }
    __syncthreads();   // vmcnt(0) drain -> buf0 ready

    #pragma unroll 1
    for (int p = 0; p < 4; ++p) {
        const __bf16* Ab0 = halo + (p & 1) * (NH2 * 16) + arow0 * 16 + halfk * 8;
        const __bf16* Bg0 = Wt4 + (size_t)p * 27648 + lrow * 16 + halfk * 8;

        // ---- issue next pass's halo DMA into the other buffer ----
        if (p < 3) {
            char* dst = (char*)halo + ((p + 1) & 1) * (NH2 * 16 * 2);
            #pragma unroll
            for (int it = 0; it < 6; ++it) {
                int task = it * 128 + tid;
                if (task < NH2 * 2) {
                    int r  = task >> 1;
                    int hl = task & 1;
                    int idx = ridx[r];
                    const __bf16* src = (idx >= 0)
                        ? featsB + (size_t)idx * 64 + (p + 1) * 16 + hl * 8
                        : zrow;
                    GLD_LDS16(src, dst + task * 16);
                }
            }
        }

        // ---- 9 (dy,dx) groups: 4 hoisted A rows shared across 3 dz taps ----
        #pragma unroll
        for (int g = 0; g < 9; ++g) {
            const int rb = ((g / 3 - 1) * HX + (g % 3 - 1)) * 16;
            // distinct halo z-rows: arow0 + {-1,0,1,2}*HXY (m0: -1..1, m1: 0..2)
            bf16x8 az0 = *(const bf16x8*)(Ab0 + rb - HXY * 16);
            bf16x8 az1 = *(const bf16x8*)(Ab0 + rb);
            bf16x8 az2 = *(const bf16x8*)(Ab0 + rb + HXY * 16);
            bf16x8 az3 = *(const bf16x8*)(Ab0 + rb + 2 * HXY * 16);
            // anti-rematerialization fence: values become asm outputs, the
            // backend can't re-derive them by re-reading LDS. No code emitted.
            asm volatile("" : "+v"(az0), "+v"(az1), "+v"(az2), "+v"(az3));
            {   // dz = 0, tap t = g
                bf16x8 b0 = *(const bf16x8*)(Bg0 + g * 1024);
                bf16x8 b1 = *(const bf16x8*)(Bg0 + g * 1024 + 512);
                acc00 = __builtin_amdgcn_mfma_f32_32x32x16_bf16(az0, b0, acc00, 0, 0, 0);
                acc01 = __builtin_amdgcn_mfma_f32_32x32x16_bf16(az0, b1, acc01, 0, 0, 0);
                acc10 = __builtin_amdgcn_mfma_f32_32x32x16_bf16(az1, b0, acc10, 0, 0, 0);
                acc11 = __builtin_amdgcn_mfma_f32_32x32x16_bf16(az1, b1, acc11, 0, 0, 0);
            }
            {   // dz = 1, tap t = 9 + g
                bf16x8 b0 = *(const bf16x8*)(Bg0 + (9 + g) * 1024);
                bf16x8 b1 = *(const bf16x8*)(Bg0 + (9 + g) * 1024 + 512);
                acc00 = __builtin_amdgcn_mfma_f32_32x32x16_bf16(az1, b0, acc00, 0, 0, 0);
                acc01 = __builtin_amdgcn_mfma_f32_32x32x16_bf16(az1, b1, acc01, 0, 0, 0);
                acc10 = __builtin_amdgcn_mfma_f32_32x32x16_bf16(az2, b0, acc10, 0, 0, 0);
                acc11 = __builtin_amdgcn_mfma_f32_32x32x16_bf16(az2, b1, acc11, 0, 0, 0);
            }
            {   // dz = 2, tap t = 18 + g
                bf16x8 b0 = *(const bf16x8*)(Bg0 + (18 + g) * 1024);
                bf16x8 b1 = *(const bf16x8*)(Bg0 + (18 + g) * 1024 + 512);
                acc00 = __builtin_amdgcn_mfma_f32_32x32x16_bf16(az2, b0, acc00, 0, 0, 0);
                acc01 = __builtin_amdgcn_mfma_f32_32x32x16_bf16(az2, b1, acc01, 0, 0, 0);
                acc10 = __builtin_amdgcn_mfma_f32_32x32x16_bf16(az3, b0, acc10, 0, 0, 0);
                acc11 = __builtin_amdgcn_mfma_f32_32x32x16_bf16(az3, b1, acc11, 0, 0, 0);
            }
        }

        // one barrier: retires next-pass DMA + closes this buffer
        if (p < 3) __syncthreads();
    }

    // ---- epilogue: C/D layout col=lane&31, row=(reg&3)+8*(reg>>2)+4*(lane>>5) ----
    const int col0 = lrow, col1 = 32 + lrow;
    const float bv0 = bias[col0], bv1 = bias[col1];
    #pragma unroll
    for (int r = 0; r < 16; ++r) {
        int mrow = (r & 3) + 8 * (r >> 2) + 4 * halfk;
        int o0 = obuf[(2*wave)     * 32 + mrow];
        int o1 = obuf[(2*wave + 1) * 32 + mrow];
        if (o0 >= 0) {
            out[(size_t)o0 * 64 + col0] = acc00[r] + bv0;
            out[(size_t)o0 * 64 + col1] = acc01[r] + bv1;
        }
        if (o1 >= 0) {
            out[(size_t)o1 * 64 + col0] = acc10[r] + bv0;
            out[(size_t)o1 * 64 + col1] = acc11[r] + bv1;
        }
    }
}

extern "C" void kernel_launch(void* const* d_in, const int* in_sizes, int n_in,
                              void* d_out, int out_size, void* d_ws, size_t ws_size,
                              hipStream_t stream) {
    const float* feats = (const float*)d_in[0];
    const float* ipos  = (const float*)d_in[1];
    const float* opos  = (const float*)d_in[2];
    const float* vsp   = (const float*)d_in[3];
    const float* W     = (const float*)d_in[4];
    const float* bias  = (const float*)d_in[5];

    int N = in_sizes[0] / 64;
    int M = out_size / 64;

    // workspace: imap | omap | ikey | okey | Wt4 | zrow | featsB (~15.5 MB)
    int*    imap   = (int*)d_ws;
    int*    omap   = imap + NROWS;
    int*    ikey   = omap + NROWS;
    int*    okey   = ikey + N;
    __bf16* Wt4    = (__bf16*)(okey + M);
    __bf16* zrow   = Wt4 + K3CC;
    __bf16* featsB = zrow + 32;

    int total = N + M + K3CC + 32 + N * 8;
    prep_kernel<<<(total + 255) / 256, 256, 0, stream>>>(ipos, N, opos, M, vsp, W, feats,
                                                         imap, ikey, omap, okey,
                                                         Wt4, zrow, featsB);
    conv_kernel<<<8 * SLABH, 128, 0, stream>>>(featsB, Wt4, zrow, bias,
                                               imap, ikey, omap, okey,
                                               (float*)d_out, N, M);
}

// Round 15
// 131.614 us; speedup vs baseline: 1.0326x; 1.0326x over previous
//
#include <hip/hip_runtime.h>
#include <math.h>

// ---- geometry ----
// Grid 50^3, coords shifted +1 -> occupy [1,50]. Dense key = (z*GY+y)*64+x.
#define GY 54
#define ZD 58
#define NROWS (ZD*GY*64)      // 200448 keys

// half-brick 8x4x4 = 128 outputs per block (2 waves); halo 10x6x6 = 360 rows.
// r12: 637 full bricks -> 125 CUs at 12 waves vs avg 9.95 (17-20% imbalance
// tail). 1183 half-bricks -> critical CU 10 waves, avg 9.24. Best measured.
#define HX 10
#define HY 6
#define HXY 60                // halo rows per z-slice
#define NH2 360               // halo rows per half-brick
#define NBX 7
#define NBY 13
#define NBZ2 13               // z-bricks of 4 output slices (covers z 1..52)
#define NBLK (NBX*NBY*NBZ2)   // 1183
#define SLABH 148             // ceil(1183/8)

#define K3CC (27*64*64)       // 110592 weight elements

typedef __bf16  bf16x8 __attribute__((ext_vector_type(8)));
typedef float  f32x16 __attribute__((ext_vector_type(16)));

// global->LDS DMA, 16B per lane, linear LDS dest (wave-uniform base + lane*16)
#define AS1 __attribute__((address_space(1)))
#define AS3 __attribute__((address_space(3)))
#define GLD_LDS16(g, l) \
    __builtin_amdgcn_global_load_lds((const AS1 void*)(g), (AS3 void*)(l), 16, 0, 0)

// ---- fused prep: maps + reverse keys + Wt4 + feats->bf16 + zero row ----
__global__ void prep_kernel(const float* __restrict__ ipos, int n,
                            const float* __restrict__ opos, int m,
                            const float* __restrict__ vsp,
                            const float* __restrict__ W,
                            const float* __restrict__ feats,
                            int* __restrict__ imap, int* __restrict__ ikey,
                            int* __restrict__ omap, int* __restrict__ okey,
                            __bf16* __restrict__ Wt4,
                            __bf16* __restrict__ zrow,
                            __bf16* __restrict__ featsB) {
    int i = blockIdx.x * 256 + threadIdx.x;
    float vs = vsp[0];
    if (i < n) {
        int x = (int)floorf(ipos[3*i+0] / vs) + 1;
        int y = (int)floorf(ipos[3*i+1] / vs) + 1;
        int z = (int)floorf(ipos[3*i+2] / vs) + 1;
        int key = (z * GY + y) * 64 + x;
        ikey[i] = key;
        imap[key] = i;
    } else if (i < n + m) {
        int j = i - n;
        int x = (int)floorf(opos[3*j+0] / vs) + 1;
        int y = (int)floorf(opos[3*j+1] / vs) + 1;
        int z = (int)floorf(opos[3*j+2] / vs) + 1;
        int key = (z * GY + y) * 64 + x;
        okey[j] = key;
        omap[key] = j;
    } else if (i < n + m + K3CC) {
        int k  = i - n - m;
        int t  = k >> 12;
        int r  = k & 4095;
        int ci = r >> 6;
        int co = r & 63;
        int p   = ci >> 4;
        int cil = ci & 15;
        Wt4[(((p * 27 + t) << 6) + co) * 16 + cil] = (__bf16)W[k];
    } else if (i < n + m + K3CC + 32) {
        zrow[i - n - m - K3CC] = (__bf16)0.f;
    } else {
        int j = i - n - m - K3CC - 32;         // one bf16x8 chunk of featsB
        if (j < n * 8) {
            const float4* s = (const float4*)(feats + (size_t)j * 8);
            float4 f0 = s[0], f1 = s[1];
            bf16x8 v;
            v[0]=(__bf16)f0.x; v[1]=(__bf16)f0.y; v[2]=(__bf16)f0.z; v[3]=(__bf16)f0.w;
            v[4]=(__bf16)f1.x; v[5]=(__bf16)f1.y; v[6]=(__bf16)f1.z; v[7]=(__bf16)f1.w;
            *(bf16x8*)(featsB + (size_t)j * 8) = v;
        }
    }
}

// FINAL (= r12, session best: 132.94us total / 50.1us conv).
// Closed models from the 15-round ledger:
//  * SQ_LDS_BANK_CONFLICT @32B row stride = exactly 8/read = wave64-b128
//    serialization floor (1024B / 128B-per-cyc); unfixable, 3 swizzles null.
//  * B-loads: compiler already pipelines (explicit ring = exact null).
//  * Manual ILP (A-prefetch/setprio): -7%. m-split: -12%. split-K: -48%.
//  * z-reuse A-hoisting: backend rematerializes ds_reads regardless of
//    ternary-free bodies or "+v" asm fences (3 attempts, counter identical).
//  * min-waves>=3 spills the 64-reg acc (2 episodes): never cap tighter.
// Regime: sum-of-pipes at 2.3 waves/SIMD -- TA ~15us + LDS ~13us + MFMA
// ~13us + VALU ~4.5us ~= 45us vs 50 measured; no remaining named lever.
__global__ __launch_bounds__(128, 2) void conv_kernel(
    const __bf16* __restrict__ featsB,  // [N,64] bf16
    const __bf16* __restrict__ Wt4,     // [4][27][64cout][16cin]
    const __bf16* __restrict__ zrow,    // 32 zero bf16
    const float* __restrict__ bias,     // [64]
    const int*   __restrict__ imap,
    const int*   __restrict__ ikey,
    const int*   __restrict__ omap,
    const int*   __restrict__ okey,
    float*       __restrict__ out,      // [M,64]
    int N, int M)
{
    __shared__ __align__(16) __bf16 halo[2 * NH2 * 16];       // 23040 B (double-buffered)
    __shared__ int ridx[NH2];                                 //  1440 B
    __shared__ int obuf[128];                                 //   512 B
    // total ~25.0 KB -> 6 blocks/CU capacity; grid needs ~4.6 -> all co-resident

    const int tid = threadIdx.x;

    // XCD slab swizzle
    int q = (blockIdx.x & 7) * SLABH + (blockIdx.x >> 3);
    if (q >= NBLK) return;   // block-uniform exit before any barrier
    const int bx = q % NBX;
    int rem = q / NBX;
    const int by  = rem % NBY;
    const int bz2 = rem / NBY;          // z-origin = bz2*4

    // ---- resolve halo row indices (validated) + output rows ----
    #pragma unroll
    for (int it = 0; it < 3; ++it) {
        int r = it * 128 + tid;
        if (r < NH2) {
            int xs = r % HX;
            int t2 = r / HX;
            int ys = t2 % HY;
            int zs = t2 / HY;           // [0,6)
            int key = ((bz2*4 + zs) * GY + (by*4 + ys)) * 64 + (bx*8 + xs);
            int idx = imap[key];
            int c = min(max(idx, 0), N - 1);
            ridx[r] = (idx >= 0 && idx < N && ikey[c] == key) ? idx : -1;
        }
    }
    {
        int x = tid & 7, y = (tid >> 3) & 3, z2 = tid >> 5;   // z2 in [0,4)
        int key = ((bz2*4 + z2 + 1) * GY + (by*4 + y + 1)) * 64 + (bx*8 + x + 1);
        int o = omap[key];
        int c = min(max(o, 0), M - 1);
        obuf[tid] = (o >= 0 && o < M && okey[c] == key) ? o : -1;
    }

    // compute roles: wave w (of 2) owns output z-slices {2w, 2w+1} x both n-tiles
    const int wave  = tid >> 6;         // {0,1}
    const int lane  = tid & 63;
    const int lrow  = lane & 31;
    const int halfk = lane >> 5;
    const int xv = lrow & 7, yv = (lrow >> 3) & 3;
    const int arow0 = (2*wave + 1) * HXY + (yv + 1) * HX + (xv + 1);

    f32x16 acc00, acc01, acc10, acc11;
    #pragma unroll
    for (int i = 0; i < 16; ++i) { acc00[i]=0.f; acc01[i]=0.f; acc10[i]=0.f; acc11[i]=0.f; }

    __syncthreads();   // ridx + obuf visible

    // ---- prologue: DMA halo quarter p=0 into buf0 (720 tasks) ----
    #pragma unroll
    for (int it = 0; it < 6; ++it) {
        int task = it * 128 + tid;
        if (task < NH2 * 2) {
            int r  = task >> 1;
            int hl = task & 1;
            int idx = ridx[r];
            const __bf16* src = (idx >= 0) ? featsB + (size_t)idx * 64 + hl * 8
                                           : zrow;
            GLD_LDS16(src, (char*)halo + task * 16);
        }
    }
    __syncthreads();   // vmcnt(0) drain -> buf0 ready

    #pragma unroll 1
    for (int p = 0; p < 4; ++p) {
        const __bf16* Ab0 = halo + (p & 1) * (NH2 * 16) + arow0 * 16 + halfk * 8;
        const __bf16* Bg0 = Wt4 + (size_t)p * 27648 + lrow * 16 + halfk * 8;

        // ---- issue next pass's halo DMA into the other buffer ----
        if (p < 3) {
            char* dst = (char*)halo + ((p + 1) & 1) * (NH2 * 16 * 2);
            #pragma unroll
            for (int it = 0; it < 6; ++it) {
                int task = it * 128 + tid;
                if (task < NH2 * 2) {
                    int r  = task >> 1;
                    int hl = task & 1;
                    int idx = ridx[r];
                    const __bf16* src = (idx >= 0)
                        ? featsB + (size_t)idx * 64 + (p + 1) * 16 + hl * 8
                        : zrow;
                    GLD_LDS16(src, dst + task * 16);
                }
            }
        }

        // ---- 27 taps: A from LDS, B from global (compiler-pipelined) ----
        #pragma unroll
        for (int t = 0; t < 27; ++t) {
            const int drow = (t/9 - 1)*HXY + ((t/3)%3 - 1)*HX + (t%3 - 1);
            bf16x8 a0 = *(const bf16x8*)(Ab0 + drow * 16);
            bf16x8 a1 = *(const bf16x8*)(Ab0 + (drow + HXY) * 16);
            bf16x8 b0 = *(const bf16x8*)(Bg0 + t * 1024);
            bf16x8 b1 = *(const bf16x8*)(Bg0 + t * 1024 + 512);
            acc00 = __builtin_amdgcn_mfma_f32_32x32x16_bf16(a0, b0, acc00, 0, 0, 0);
            acc01 = __builtin_amdgcn_mfma_f32_32x32x16_bf16(a0, b1, acc01, 0, 0, 0);
            acc10 = __builtin_amdgcn_mfma_f32_32x32x16_bf16(a1, b0, acc10, 0, 0, 0);
            acc11 = __builtin_amdgcn_mfma_f32_32x32x16_bf16(a1, b1, acc11, 0, 0, 0);
        }

        // one barrier: retires next-pass DMA + closes this buffer
        if (p < 3) __syncthreads();
    }

    // ---- epilogue: C/D layout col=lane&31, row=(reg&3)+8*(reg>>2)+4*(lane>>5) ----
    const int col0 = lrow, col1 = 32 + lrow;
    const float bv0 = bias[col0], bv1 = bias[col1];
    #pragma unroll
    for (int r = 0; r < 16; ++r) {
        int mrow = (r & 3) + 8 * (r >> 2) + 4 * halfk;
        int o0 = obuf[(2*wave)     * 32 + mrow];
        int o1 = obuf[(2*wave + 1) * 32 + mrow];
        if (o0 >= 0) {
            out[(size_t)o0 * 64 + col0] = acc00[r] + bv0;
            out[(size_t)o0 * 64 + col1] = acc01[r] + bv1;
        }
        if (o1 >= 0) {
            out[(size_t)o1 * 64 + col0] = acc10[r] + bv0;
            out[(size_t)o1 * 64 + col1] = acc11[r] + bv1;
        }
    }
}

extern "C" void kernel_launch(void* const* d_in, const int* in_sizes, int n_in,
                              void* d_out, int out_size, void* d_ws, size_t ws_size,
                              hipStream_t stream) {
    const float* feats = (const float*)d_in[0];
    const float* ipos  = (const float*)d_in[1];
    const float* opos  = (const float*)d_in[2];
    const float* vsp   = (const float*)d_in[3];
    const float* W     = (const float*)d_in[4];
    const float* bias  = (const float*)d_in[5];

    int N = in_sizes[0] / 64;
    int M = out_size / 64;

    // workspace: imap | omap | ikey | okey | Wt4 | zrow | featsB (~15.5 MB)
    int*    imap   = (int*)d_ws;
    int*    omap   = imap + NROWS;
    int*    ikey   = omap + NROWS;
    int*    okey   = ikey + N;
    __bf16* Wt4    = (__bf16*)(okey + M);
    __bf16* zrow   = Wt4 + K3CC;
    __bf16* featsB = zrow + 32;

    int total = N + M + K3CC + 32 + N * 8;
    prep_kernel<<<(total + 255) / 256, 256, 0, stream>>>(ipos, N, opos, M, vsp, W, feats,
                                                         imap, ikey, omap, okey,
                                                         Wt4, zrow, featsB);
    conv_kernel<<<8 * SLABH, 128, 0, stream>>>(featsB, Wt4, zrow, bias,
                                               imap, ikey, omap, okey,
                                               (float*)d_out, N, M);
}